// Round 5
// baseline (1014.604 us; speedup 1.0000x reference)
//
#include <hip/hip_runtime.h>
#include <math.h>

#define NSP 262144  // 64^3
static constexpr float TWO_PI_OVER_64 = 0.09817477042468103f;

// ===========================================================================
// Layer-0 front end: DFT (W then H) of the 2 raw input channels.
// ===========================================================================
__global__ __launch_bounds__(256) void k_fwd_wh2(const float* __restrict__ vel,
                                                 const float* __restrict__ ptt,
                                                 float2* __restrict__ VP2) {
  __shared__ float plane[64][65];
  __shared__ float2 A[64][8];
  __shared__ float2 tw[64];
  int t = threadIdx.x;
  if (t < 64) { float s, c; sincosf(TWO_PI_OVER_64 * t, &s, &c); tw[t] = make_float2(c, s); }
  int b = blockIdx.x >> 7, ch = (blockIdx.x >> 6) & 1, d = blockIdx.x & 63;
  const float4* src = (const float4*)((ch ? ptt : vel) + (size_t)b * NSP + d * 4096);
  for (int p = 0; p < 4; ++p) {
    int i = t + 256 * p;
    float4 v = src[i];
    int h = i >> 4, sg = (i & 15) * 4;
    plane[h][sg] = v.x; plane[h][sg + 1] = v.y; plane[h][sg + 2] = v.z; plane[h][sg + 3] = v.w;
  }
  __syncthreads();
  for (int p = 0; p < 2; ++p) {
    int o = t + 256 * p;
    int h = o >> 3, kw = o & 7;
    float re = 0.f, im = 0.f;
    for (int w = 0; w < 64; ++w) {
      float2 cs = tw[(kw * w) & 63];
      float v = plane[h][w];
      re += v * cs.x; im -= v * cs.y;
    }
    A[h][kw] = make_float2(re, im);
  }
  __syncthreads();
  if (t < 128) {
    int kh = t >> 3, kw = t & 7;
    int f = (kh < 8) ? kh : kh + 48;
    float re = 0.f, im = 0.f;
    for (int h = 0; h < 64; ++h) {
      float2 cs = tw[(h * f) & 63];
      float2 a = A[h][kw];
      re += a.x * cs.x + a.y * cs.y;
      im += a.y * cs.x - a.x * cs.y;
    }
    VP2[(size_t)blockIdx.x * 128 + t] = make_float2(re, im);
  }
}

// ===========================================================================
// Layer-0: DFT along D of the 2 channels + fold lift -> X3[b,ci,kd,kh,kw]
// ===========================================================================
__global__ __launch_bounds__(256) void k_fwd_d_lift(const float2* __restrict__ VP2,
                                                    const float* __restrict__ lw,
                                                    const float* __restrict__ lb,
                                                    float2* __restrict__ X3) {
  __shared__ float2 tile[2][64][8];
  __shared__ float2 F[2][16][8];
  __shared__ float2 tw[64];
  int t = threadIdx.x;
  if (t < 64) { float s, c; sincosf(TWO_PI_OVER_64 * t, &s, &c); tw[t] = make_float2(c, s); }
  int b = blockIdx.x >> 4, kh = blockIdx.x & 15;
  for (int p = 0; p < 4; ++p) {
    int i = t + 256 * p;
    int ch = i >> 9, dd = (i >> 3) & 63, kw = i & 7;
    tile[ch][dd][kw] = VP2[(size_t)((b * 2 + ch) * 64 + dd) * 128 + kh * 8 + kw];
  }
  __syncthreads();
  { int ch = t >> 7, kd = (t >> 3) & 15, kw = t & 7;
    int f = (kd < 8) ? kd : kd + 48;
    float re = 0.f, im = 0.f;
    for (int dd = 0; dd < 64; ++dd) {
      float2 cs = tw[(dd * f) & 63];
      float2 v = tile[ch][dd][kw];
      re += v.x * cs.x + v.y * cs.y;
      im += v.y * cs.x - v.x * cs.y;
    }
    F[ch][kd][kw] = make_float2(re, im); }
  __syncthreads();
  for (int p = 0; p < 16; ++p) {
    int o = t + 256 * p;
    int ci = o >> 7, kd = (o >> 3) & 15, kw = o & 7;
    float2 f0 = F[0][kd][kw], f1 = F[1][kd][kw];
    float w0 = lw[ci], w1 = lw[32 + ci];
    float2 v = make_float2(w0 * f0.x + w1 * f1.x, w0 * f0.y + w1 * f1.y);
    if (kh == 0 && kd == 0 && kw == 0) v.x += lb[ci] * 262144.f;
    X3[(size_t)(b * 32 + ci) * 2048 + kd * 128 + kh * 8 + kw] = v;
  }
}

// ===========================================================================
// Forward DFT along H (layers 1,2): X1 -> X2  (table gather — R2 version)
// ===========================================================================
__global__ __launch_bounds__(128) void k_fwd_h(const float2* __restrict__ X1,
                                               float2* __restrict__ X2) {
  __shared__ float2 tile[64][8];
  __shared__ float2 tw[64];
  int t = threadIdx.x;
  if (t < 64) { float s, c; sincosf(TWO_PI_OVER_64 * t, &s, &c); tw[t] = make_float2(c, s); }
  const float4* s4 = (const float4*)(X1 + (size_t)blockIdx.x * 512);
  float4* t4 = (float4*)tile;
  t4[t] = s4[t];
  t4[t + 128] = s4[t + 128];
  __syncthreads();
  int kh = t >> 3, k = t & 7;
  int f = (kh < 8) ? kh : kh + 48;
  float re = 0.f, im = 0.f;
#pragma unroll 8
  for (int h = 0; h < 64; ++h) {
    float2 cs = tw[(h * f) & 63];
    float2 v = tile[h][k];
    re += v.x * cs.x + v.y * cs.y;
    im += v.y * cs.x - v.x * cs.y;
  }
  X2[(size_t)blockIdx.x * 128 + t] = make_float2(re, im);
}

// ===========================================================================
// Forward DFT along D (layers 1,2): X2 -> X3  (table gather — R2 version)
// ===========================================================================
__global__ __launch_bounds__(128) void k_fwd_d(const float2* __restrict__ X2,
                                               float2* __restrict__ X3) {
  __shared__ float2 tile[64][8];
  __shared__ float2 tw[64];
  int t = threadIdx.x;
  if (t < 64) { float s, c; sincosf(TWO_PI_OVER_64 * t, &s, &c); tw[t] = make_float2(c, s); }
  int kh = blockIdx.x & 15, bc = blockIdx.x >> 4;
  const float2* src = X2 + (size_t)bc * 8192 + kh * 8;
  for (int i = t; i < 512; i += 128) tile[i >> 3][i & 7] = src[(i >> 3) * 128 + (i & 7)];
  __syncthreads();
  int kd = t >> 3, k = t & 7;
  int f = (kd < 8) ? kd : kd + 48;
  float re = 0.f, im = 0.f;
#pragma unroll 8
  for (int d = 0; d < 64; ++d) {
    float2 cs = tw[(d * f) & 63];
    float2 v = tile[d][k];
    re += v.x * cs.x + v.y * cs.y;
    im += v.y * cs.x - v.x * cs.y;
  }
  X3[(size_t)bc * 2048 + kd * 128 + kh * 8 + k] = make_float2(re, im);
}

// ===========================================================================
// Mode mixing
// ===========================================================================
__global__ __launch_bounds__(256) void k_mix(const float2* __restrict__ X3,
                                             const float* __restrict__ wr,
                                             const float* __restrict__ wi,
                                             float2* __restrict__ Y3) {
  __shared__ float2 xs[4][32][8];
  int t = threadIdx.x;
  int kd = blockIdx.x >> 4, kh = blockIdx.x & 15;
  for (int i = t; i < 1024; i += 256) {
    int b = i >> 8, ci = (i >> 3) & 31, k = i & 7;
    xs[b][ci][k] = X3[(size_t)(b * 32 + ci) * 2048 + kd * 128 + kh * 8 + k];
  }
  __syncthreads();
  int corner = ((kd >= 8) ? 2 : 0) + ((kh >= 8) ? 1 : 0);
  int md = kd & 7, mh = kh & 7;
  int co = t >> 3, k = t & 7;
  size_t wbase = (size_t)corner * 32 * 32 * 512 + (size_t)md * 64 + (size_t)mh * 8 + k;
  float ar0 = 0, ai0 = 0, ar1 = 0, ai1 = 0, ar2 = 0, ai2 = 0, ar3 = 0, ai3 = 0;
  for (int ci = 0; ci < 32; ++ci) {
    size_t o = wbase + (size_t)(ci * 32 + co) * 512;
    float wre = wr[o], wim = wi[o];
    float2 v0 = xs[0][ci][k], v1 = xs[1][ci][k];
    float2 v2 = xs[2][ci][k], v3 = xs[3][ci][k];
    ar0 += v0.x * wre - v0.y * wim;  ai0 += v0.x * wim + v0.y * wre;
    ar1 += v1.x * wre - v1.y * wim;  ai1 += v1.x * wim + v1.y * wre;
    ar2 += v2.x * wre - v2.y * wim;  ai2 += v2.x * wim + v2.y * wre;
    ar3 += v3.x * wre - v3.y * wim;  ai3 += v3.x * wim + v3.y * wre;
  }
  size_t obase = (size_t)kd * 128 + kh * 8 + k;
  Y3[(size_t)(0 * 32 + co) * 2048 + obase] = make_float2(ar0, ai0);
  Y3[(size_t)(1 * 32 + co) * 2048 + obase] = make_float2(ar1, ai1);
  Y3[(size_t)(2 * 32 + co) * 2048 + obase] = make_float2(ar2, ai2);
  Y3[(size_t)(3 * 32 + co) * 2048 + obase] = make_float2(ar3, ai3);
}

// ===========================================================================
// Fused inverse DFT along D then H: Y3 -> Z2 (into S buffer)
// ===========================================================================
__global__ __launch_bounds__(256) void k_inv_dh(const float2* __restrict__ Y3,
                                                float2* __restrict__ Z2) {
  __shared__ float2 yt[2048];
  __shared__ float2 zd[4][16][8];
  __shared__ float2 tw[64];
  int t = threadIdx.x;
  if (t < 64) { float s, c; sincosf(TWO_PI_OVER_64 * t, &s, &c); tw[t] = make_float2(c, s); }
  int bc = blockIdx.x >> 4, d0 = (blockIdx.x & 15) * 4;
  const float4* y4 = (const float4*)(Y3 + (size_t)bc * 2048);
  float4* yt4 = (float4*)yt;
  for (int p = 0; p < 4; ++p) yt4[t + 256 * p] = y4[t + 256 * p];
  __syncthreads();
  const float sc = 1.f / 262144.f;
  for (int p = 0; p < 2; ++p) {
    int o = t + 256 * p;
    int dd = o >> 7, kh = (o >> 3) & 15, kw = o & 7;
    int d = d0 + dd;
    float re = 0.f, im = 0.f;
#pragma unroll
    for (int kd = 0; kd < 16; ++kd) {
      int f = (kd < 8) ? kd : kd + 48;
      float2 cs = tw[(d * f) & 63];
      float2 v = yt[kd * 128 + kh * 8 + kw];
      re += v.x * cs.x - v.y * cs.y;
      im += v.x * cs.y + v.y * cs.x;
    }
    zd[dd][kh][kw] = make_float2(re * sc, im * sc);
  }
  __syncthreads();
  for (int p = 0; p < 8; ++p) {
    int o = t + 256 * p;
    int dd = o >> 9, h = (o >> 3) & 63, kw = o & 7;
    float re = 0.f, im = 0.f;
#pragma unroll
    for (int kh = 0; kh < 16; ++kh) {
      int f = (kh < 8) ? kh : kh + 48;
      float2 cs = tw[(h * f) & 63];
      float2 v = zd[dd][kh][kw];
      re += v.x * cs.x - v.y * cs.y;
      im += v.x * cs.y + v.y * cs.x;
    }
    Z2[((size_t)bc * 64 + d0 + dd) * 512 + h * 8 + kw] = make_float2(re, im);
  }
}

// ===========================================================================
// Tail v5: co-blocking x4.  128 threads = (cog:8, hh:2, ws:8); each thread
// computes 4 co x 8 w x 1 h.  Same 25.6 KB LDS as v4 but half the DS instrs.
// irfft twiddles by register recurrence; fwd-W by register partials + 8-lane
// reduce-scatter shuffle.  grid = (b, d, h/2) = 8192 blocks.
// MODE 0: inputs = vel/ptt with folded lift+skip; writes x, S (in place)
// MODE 1: inputs = x;                             writes x, S (in place)
// MODE 2: inputs = x;                             channel-sum -> pr (atomics)
// ===========================================================================
template <int MODE>
__global__ __launch_bounds__(128, 3) void k_tail(
    const float2* __restrict__ S, const float* __restrict__ xin,
    const float* __restrict__ pttin, const float* __restrict__ lw,
    const float* __restrict__ lb, const float* __restrict__ skw,
    const float* __restrict__ skb, float* __restrict__ xout,
    float2* __restrict__ Sout, float* __restrict__ pr) {
  __shared__ float2 tws[64];
  __shared__ float2 zt[32][2][9];
  __shared__ float sw[(MODE == 0) ? 3 : 32][32];
  __shared__ float xt[(MODE == 0) ? 2 : 32][2][64];
  int t = threadIdx.x;
  if (t < 64) { float s, c; sincosf(TWO_PI_OVER_64 * t, &s, &c); tws[t] = make_float2(c, s); }
  int b = blockIdx.x >> 11, d = (blockIdx.x >> 5) & 63, h0 = (blockIdx.x & 31) * 2;
  {  // Z2 tile: thread (co, sub) loads k=2sub,2sub+1 for both h rows
    int co = t >> 2, sub = t & 3;
    const float4* S4 = (const float4*)S;
    size_t base = (size_t)((b * 32 + co) * 64 + d) * 256;
#pragma unroll
    for (int hh = 0; hh < 2; ++hh) {
      float4 v = S4[base + (h0 + hh) * 4 + sub];
      zt[co][hh][2 * sub] = make_float2(v.x, v.y);
      zt[co][hh][2 * sub + 1] = make_float2(v.z, v.w);
    }
  }
  if constexpr (MODE == 0) {
    if (t < 64) {
      int ch = t >> 5, hh = (t >> 4) & 1, sg = t & 15;
      const float4* src = (const float4*)(ch ? pttin : xin);
      *(float4*)&xt[ch][hh][sg * 4] =
          src[((size_t)b * NSP + d * 4096 + (h0 + hh) * 64) / 4 + sg];
    } else {
      for (int i = t - 64; i < 96; i += 64) {
        int r = i >> 5, co = i & 31;
        if (r < 2) {
          float a = 0.f;
          for (int ci = 0; ci < 32; ++ci) a += lw[r * 32 + ci] * skw[ci * 32 + co];
          sw[r][co] = a;
        } else {
          float a = skb[co];
          for (int ci = 0; ci < 32; ++ci) a += lb[ci] * skw[ci * 32 + co];
          sw[2][co] = a;
        }
      }
    }
  } else {
    ((float4*)sw)[t] = ((const float4*)skw)[t];
    ((float4*)sw)[t + 128] = ((const float4*)skw)[t + 128];
    for (int p = 0; p < 8; ++p) {
      int idx = t + 128 * p, row = idx >> 4, ci = row >> 1, hh = row & 1, sg = idx & 15;
      *(float4*)&xt[ci][hh][sg * 4] =
          ((const float4*)xin)[(size_t)(((b * 32 + ci) * 64 + d) * 64 + h0 + hh) * 16 + sg];
    }
  }
  __syncthreads();

  int cog = t >> 4, hh = (t >> 3) & 1, ws = t & 7;
  int co0 = cog * 4;
  float2 e1[8];
#pragma unroll
  for (int j = 0; j < 8; ++j) e1[j] = tws[8 * ws + j];
  float bias[4];
#pragma unroll
  for (int r = 0; r < 4; ++r)
    bias[r] = (MODE == 0) ? sw[2][co0 + r] : skb[co0 + r];

  // ---- irfft along W (twiddle recurrence, shared across 4 co) ----
  float acc[4][8];
#pragma unroll
  for (int r = 0; r < 4; ++r) {
    float z0 = zt[co0 + r][hh][0].x + bias[r];
#pragma unroll
    for (int j = 0; j < 8; ++j) acc[r][j] = z0;
  }
  {
    float2 cur[8];
#pragma unroll
    for (int j = 0; j < 8; ++j) cur[j] = e1[j];
#pragma unroll
    for (int k = 1; k < 8; ++k) {
      float2 z[4];
#pragma unroll
      for (int r = 0; r < 4; ++r) z[r] = zt[co0 + r][hh][k];
#pragma unroll
      for (int r = 0; r < 4; ++r)
#pragma unroll
        for (int j = 0; j < 8; ++j)
          acc[r][j] += 2.f * (z[r].x * cur[j].x - z[r].y * cur[j].y);
      if (k < 7)
#pragma unroll
        for (int j = 0; j < 8; ++j) {
          float cx = cur[j].x * e1[j].x - cur[j].y * e1[j].y;
          cur[j].y = cur[j].x * e1[j].y + cur[j].y * e1[j].x;
          cur[j].x = cx;
        }
    }
  }
  // ---- skip ----
  constexpr int NCI = (MODE == 0) ? 2 : 32;
#pragma unroll 4
  for (int ci = 0; ci < NCI; ++ci) {
    float4 sv = *(const float4*)&sw[ci][co0];
    float4 xa = *(const float4*)&xt[ci][hh][8 * ws];
    float4 xb = *(const float4*)&xt[ci][hh][8 * ws + 4];
    float xv[8] = {xa.x, xa.y, xa.z, xa.w, xb.x, xb.y, xb.z, xb.w};
    float svv[4] = {sv.x, sv.y, sv.z, sv.w};
#pragma unroll
    for (int r = 0; r < 4; ++r)
#pragma unroll
      for (int j = 0; j < 8; ++j) acc[r][j] += xv[j] * svv[r];
  }
  // ---- gelu ----
#pragma unroll
  for (int r = 0; r < 4; ++r)
#pragma unroll
    for (int j = 0; j < 8; ++j) {
      float v = acc[r][j];
      float u = 0.7978845608028654f * (v + 0.044715f * v * v * v);
      acc[r][j] = __fdividef(v, 1.f + __expf(-2.f * u));
    }

  if constexpr (MODE == 2) {
    float rs[4];
#pragma unroll
    for (int r = 0; r < 4; ++r) {
      float s = 0.f;
#pragma unroll
      for (int j = 0; j < 8; ++j) s += acc[r][j];
      rs[r] = s;
    }
#pragma unroll
    for (int off = 1; off < 16; off <<= 1)
#pragma unroll
      for (int r = 0; r < 4; ++r) rs[r] += __shfl_xor(rs[r], off);
    if ((t & 15) == 0)
#pragma unroll
      for (int r = 0; r < 4; ++r) atomicAdd(&pr[b * 32 + co0 + r], rs[r]);
  } else {
    // ---- write x_{l+1} directly from registers ----
    float4* x4o = (float4*)xout;
#pragma unroll
    for (int r = 0; r < 4; ++r) {
      size_t o = (((size_t)(b * 32 + co0 + r) * 64 + d) * 64 + h0 + hh) * 16 + 2 * ws;
      x4o[o]     = make_float4(acc[r][0], acc[r][1], acc[r][2], acc[r][3]);
      x4o[o + 1] = make_float4(acc[r][4], acc[r][5], acc[r][6], acc[r][7]);
    }
    // ---- fused fwd-W: register partials + reduce-scatter over the 8 ws lanes
#pragma unroll
    for (int half = 0; half < 2; ++half) {
      float2 P[2][8];
#pragma unroll
      for (int rr = 0; rr < 2; ++rr)
#pragma unroll
        for (int kw = 0; kw < 8; ++kw) P[rr][kw] = make_float2(0.f, 0.f);
#pragma unroll
      for (int j = 0; j < 8; ++j) {
        float2 cc = make_float2(e1[j].x, -e1[j].y);  // e^{-i theta_j}
        float2 cur = make_float2(1.f, 0.f);
        float g0 = acc[2 * half][j], g1 = acc[2 * half + 1][j];
#pragma unroll
        for (int kw = 0; kw < 8; ++kw) {
          P[0][kw].x += g0 * cur.x;  P[0][kw].y += g0 * cur.y;
          P[1][kw].x += g1 * cur.x;  P[1][kw].y += g1 * cur.y;
          if (kw < 7) {
            float cx = cur.x * cc.x - cur.y * cc.y;
            cur.y = cur.x * cc.y + cur.y * cc.x;
            cur.x = cx;
          }
        }
      }
      float2 Q[2][4];
#pragma unroll
      for (int rr = 0; rr < 2; ++rr)
#pragma unroll
        for (int kk = 0; kk < 4; ++kk) {
          float2 keep = (ws & 4) ? P[rr][kk + 4] : P[rr][kk];
          float2 send = (ws & 4) ? P[rr][kk] : P[rr][kk + 4];
          keep.x += __shfl_xor(send.x, 4);
          keep.y += __shfl_xor(send.y, 4);
          Q[rr][kk] = keep;
        }
      float2 R[2][2];
#pragma unroll
      for (int rr = 0; rr < 2; ++rr)
#pragma unroll
        for (int kk = 0; kk < 2; ++kk) {
          float2 keep = (ws & 2) ? Q[rr][kk + 2] : Q[rr][kk];
          float2 send = (ws & 2) ? Q[rr][kk] : Q[rr][kk + 2];
          keep.x += __shfl_xor(send.x, 2);
          keep.y += __shfl_xor(send.y, 2);
          R[rr][kk] = keep;
        }
#pragma unroll
      for (int rr = 0; rr < 2; ++rr) {
        float2 keep = (ws & 1) ? R[rr][1] : R[rr][0];
        float2 send = (ws & 1) ? R[rr][0] : R[rr][1];
        keep.x += __shfl_xor(send.x, 1);
        keep.y += __shfl_xor(send.y, 1);
        Sout[((size_t)(b * 32 + co0 + 2 * half + rr) * 64 + d) * 512 + (h0 + hh) * 8 + ws] = keep;
      }
    }
  }
}

// ===========================================================================
// Head: collapsed layer-4 (DC-only spectral + skip) + proj + MLP -> out[4,3]
// ===========================================================================
__global__ __launch_bounds__(128) void k_head(const float* __restrict__ pr,
                                              const float* __restrict__ swr,
                                              const float* __restrict__ skw,
                                              const float* __restrict__ skb,
                                              const float* __restrict__ pw,
                                              const float* __restrict__ pb,
                                              const float* __restrict__ f1w,
                                              const float* __restrict__ f1b,
                                              const float* __restrict__ f2w,
                                              const float* __restrict__ f2b,
                                              const float* __restrict__ f3w,
                                              const float* __restrict__ f3b,
                                              float* __restrict__ out) {
  __shared__ float m[128], h1[128], p2[128], f1[512], f2[256];
  int t = threadIdx.x;
  m[t] = pr[t] * (1.f / 262144.f);
  __syncthreads();
  { int b = t >> 5, co = t & 31;
    float acc = skb[96 + co];
    for (int ci = 0; ci < 32; ++ci) {
      float wdc = swr[((size_t)12 * 1024 + (size_t)(ci * 32 + co)) * 512];
      acc += m[b * 32 + ci] * (wdc + skw[3072 + ci * 32 + co]);
    }
    h1[t] = acc; }
  __syncthreads();
  { int b = t >> 5, o = t & 31;
    float acc = pb[o];
    for (int c = 0; c < 32; ++c) acc += h1[b * 32 + c] * pw[c * 32 + o];
    p2[t] = acc; }
  __syncthreads();
  for (int j = 0; j < 4; ++j) {
    int idx = t + 128 * j, b = idx >> 7, o = idx & 127;
    float acc = f1b[o];
    for (int c = 0; c < 32; ++c) acc += p2[b * 32 + c] * f1w[c * 128 + o];
    f1[idx] = fmaxf(acc, 0.f);
  }
  __syncthreads();
  for (int j = 0; j < 2; ++j) {
    int idx = t + 128 * j, b = idx >> 6, o = idx & 63;
    float acc = f2b[o];
    for (int c = 0; c < 128; ++c) acc += f1[b * 128 + c] * f2w[c * 64 + o];
    f2[idx] = fmaxf(acc, 0.f);
  }
  __syncthreads();
  if (t < 12) {
    int b = t / 3, o = t % 3;
    float acc = f3b[o];
    for (int c = 0; c < 64; ++c) acc += f2[b * 64 + c] * f3w[c * 3 + o];
    out[t] = acc;
  }
}

// ===========================================================================
extern "C" void kernel_launch(void* const* d_in, const int* in_sizes, int n_in,
                              void* d_out, int out_size, void* d_ws, size_t ws_size,
                              hipStream_t stream) {
  const float* vel = (const float*)d_in[0];
  const float* ptt = (const float*)d_in[1];
  const float* lw  = (const float*)d_in[2];
  const float* lb  = (const float*)d_in[3];
  const float* swr = (const float*)d_in[4];
  const float* swi = (const float*)d_in[5];
  const float* skw = (const float*)d_in[6];
  const float* skb = (const float*)d_in[7];
  const float* pw  = (const float*)d_in[8];
  const float* pb  = (const float*)d_in[9];
  const float* f1w = (const float*)d_in[10];
  const float* f1b = (const float*)d_in[11];
  const float* f2w = (const float*)d_in[12];
  const float* f2b = (const float*)d_in[13];
  const float* f3w = (const float*)d_in[14];
  const float* f3b = (const float*)d_in[15];
  float* out = (float*)d_out;

  char* ws = (char*)d_ws;
  float*  x   = (float*)(ws);
  float2* S   = (float2*)(ws + 134217728ULL);
  float2* X2  = (float2*)(ws + 167772160ULL);
  float2* VP2 = X2;
  float2* X3  = (float2*)(ws + 176160768ULL);
  float2* Y3  = (float2*)(ws + 178257920ULL);
  float*  pr  = (float*)(ws + 180355072ULL);
  if (ws_size < 180355584ULL) return;

  hipMemsetAsync(pr, 0, 512, stream);

  // ---- layer 0 (lift folded into the 2-channel spectral path) ----
  k_fwd_wh2<<<512, 256, 0, stream>>>(vel, ptt, VP2);
  k_fwd_d_lift<<<64, 256, 0, stream>>>(VP2, lw, lb, X3);
  k_mix<<<256, 256, 0, stream>>>(X3, swr, swi, Y3);
  k_inv_dh<<<2048, 256, 0, stream>>>(Y3, S);
  k_tail<0><<<8192, 128, 0, stream>>>(S, vel, ptt, lw, lb, skw, skb, x, S, nullptr);

  // ---- layer 1 ----
  k_fwd_h<<<8192, 128, 0, stream>>>(S, X2);
  k_fwd_d<<<2048, 128, 0, stream>>>(X2, X3);
  k_mix<<<256, 256, 0, stream>>>(X3, swr + 2097152, swi + 2097152, Y3);
  k_inv_dh<<<2048, 256, 0, stream>>>(Y3, S);
  k_tail<1><<<8192, 128, 0, stream>>>(S, x, nullptr, nullptr, nullptr,
                                      skw + 1024, skb + 32, x, S, nullptr);

  // ---- layer 2 (mean fused, no x/X1 writeback) ----
  k_fwd_h<<<8192, 128, 0, stream>>>(S, X2);
  k_fwd_d<<<2048, 128, 0, stream>>>(X2, X3);
  k_mix<<<256, 256, 0, stream>>>(X3, swr + 2 * 2097152, swi + 2 * 2097152, Y3);
  k_inv_dh<<<2048, 256, 0, stream>>>(Y3, S);
  k_tail<2><<<8192, 128, 0, stream>>>(S, x, nullptr, nullptr, nullptr,
                                      skw + 2048, skb + 64, nullptr, nullptr, pr);

  // ---- collapsed layer 3 + proj + MLP head ----
  k_head<<<1, 128, 0, stream>>>(pr, swr, skw, skb, pw, pb, f1w, f1b,
                                f2w, f2b, f3w, f3b, out);
}

// Round 6
// 835.159 us; speedup vs baseline: 1.2149x; 1.2149x over previous
//
#include <hip/hip_runtime.h>
#include <math.h>

#define NSP 262144  // 64^3
static constexpr float TWO_PI_OVER_64 = 0.09817477042468103f;

// ===========================================================================
// Layer-0 front end: DFT (W then H) of the 2 raw input channels.
// ===========================================================================
__global__ __launch_bounds__(256) void k_fwd_wh2(const float* __restrict__ vel,
                                                 const float* __restrict__ ptt,
                                                 float2* __restrict__ VP2) {
  __shared__ float plane[64][65];
  __shared__ float2 A[64][8];
  __shared__ float2 tw[64];
  int t = threadIdx.x;
  if (t < 64) { float s, c; sincosf(TWO_PI_OVER_64 * t, &s, &c); tw[t] = make_float2(c, s); }
  int b = blockIdx.x >> 7, ch = (blockIdx.x >> 6) & 1, d = blockIdx.x & 63;
  const float4* src = (const float4*)((ch ? ptt : vel) + (size_t)b * NSP + d * 4096);
  for (int p = 0; p < 4; ++p) {
    int i = t + 256 * p;
    float4 v = src[i];
    int h = i >> 4, sg = (i & 15) * 4;
    plane[h][sg] = v.x; plane[h][sg + 1] = v.y; plane[h][sg + 2] = v.z; plane[h][sg + 3] = v.w;
  }
  __syncthreads();
  for (int p = 0; p < 2; ++p) {
    int o = t + 256 * p;
    int h = o >> 3, kw = o & 7;
    float re = 0.f, im = 0.f;
    for (int w = 0; w < 64; ++w) {
      float2 cs = tw[(kw * w) & 63];
      float v = plane[h][w];
      re += v * cs.x; im -= v * cs.y;
    }
    A[h][kw] = make_float2(re, im);
  }
  __syncthreads();
  if (t < 128) {
    int kh = t >> 3, kw = t & 7;
    int f = (kh < 8) ? kh : kh + 48;
    float re = 0.f, im = 0.f;
    for (int h = 0; h < 64; ++h) {
      float2 cs = tw[(h * f) & 63];
      float2 a = A[h][kw];
      re += a.x * cs.x + a.y * cs.y;
      im += a.y * cs.x - a.x * cs.y;
    }
    VP2[(size_t)blockIdx.x * 128 + t] = make_float2(re, im);
  }
}

// ===========================================================================
// Layer-0: DFT along D of the 2 channels + fold lift -> X3[b,ci,kd,kh,kw]
// ===========================================================================
__global__ __launch_bounds__(256) void k_fwd_d_lift(const float2* __restrict__ VP2,
                                                    const float* __restrict__ lw,
                                                    const float* __restrict__ lb,
                                                    float2* __restrict__ X3) {
  __shared__ float2 tile[2][64][8];
  __shared__ float2 F[2][16][8];
  __shared__ float2 tw[64];
  int t = threadIdx.x;
  if (t < 64) { float s, c; sincosf(TWO_PI_OVER_64 * t, &s, &c); tw[t] = make_float2(c, s); }
  int b = blockIdx.x >> 4, kh = blockIdx.x & 15;
  for (int p = 0; p < 4; ++p) {
    int i = t + 256 * p;
    int ch = i >> 9, dd = (i >> 3) & 63, kw = i & 7;
    tile[ch][dd][kw] = VP2[(size_t)((b * 2 + ch) * 64 + dd) * 128 + kh * 8 + kw];
  }
  __syncthreads();
  { int ch = t >> 7, kd = (t >> 3) & 15, kw = t & 7;
    int f = (kd < 8) ? kd : kd + 48;
    float re = 0.f, im = 0.f;
    for (int dd = 0; dd < 64; ++dd) {
      float2 cs = tw[(dd * f) & 63];
      float2 v = tile[ch][dd][kw];
      re += v.x * cs.x + v.y * cs.y;
      im += v.y * cs.x - v.x * cs.y;
    }
    F[ch][kd][kw] = make_float2(re, im); }
  __syncthreads();
  for (int p = 0; p < 16; ++p) {
    int o = t + 256 * p;
    int ci = o >> 7, kd = (o >> 3) & 15, kw = o & 7;
    float2 f0 = F[0][kd][kw], f1 = F[1][kd][kw];
    float w0 = lw[ci], w1 = lw[32 + ci];
    float2 v = make_float2(w0 * f0.x + w1 * f1.x, w0 * f0.y + w1 * f1.y);
    if (kh == 0 && kd == 0 && kw == 0) v.x += lb[ci] * 262144.f;
    X3[(size_t)(b * 32 + ci) * 2048 + kd * 128 + kh * 8 + kw] = v;
  }
}

// ===========================================================================
// Forward DFT along H (layers 1,2): X1 -> X2  (table gather)
// ===========================================================================
__global__ __launch_bounds__(128) void k_fwd_h(const float2* __restrict__ X1,
                                               float2* __restrict__ X2) {
  __shared__ float2 tile[64][8];
  __shared__ float2 tw[64];
  int t = threadIdx.x;
  if (t < 64) { float s, c; sincosf(TWO_PI_OVER_64 * t, &s, &c); tw[t] = make_float2(c, s); }
  const float4* s4 = (const float4*)(X1 + (size_t)blockIdx.x * 512);
  float4* t4 = (float4*)tile;
  t4[t] = s4[t];
  t4[t + 128] = s4[t + 128];
  __syncthreads();
  int kh = t >> 3, k = t & 7;
  int f = (kh < 8) ? kh : kh + 48;
  float re = 0.f, im = 0.f;
#pragma unroll 8
  for (int h = 0; h < 64; ++h) {
    float2 cs = tw[(h * f) & 63];
    float2 v = tile[h][k];
    re += v.x * cs.x + v.y * cs.y;
    im += v.y * cs.x - v.x * cs.y;
  }
  X2[(size_t)blockIdx.x * 128 + t] = make_float2(re, im);
}

// ===========================================================================
// Forward DFT along D (layers 1,2): X2 -> X3  (table gather)
// ===========================================================================
__global__ __launch_bounds__(128) void k_fwd_d(const float2* __restrict__ X2,
                                               float2* __restrict__ X3) {
  __shared__ float2 tile[64][8];
  __shared__ float2 tw[64];
  int t = threadIdx.x;
  if (t < 64) { float s, c; sincosf(TWO_PI_OVER_64 * t, &s, &c); tw[t] = make_float2(c, s); }
  int kh = blockIdx.x & 15, bc = blockIdx.x >> 4;
  const float2* src = X2 + (size_t)bc * 8192 + kh * 8;
  for (int i = t; i < 512; i += 128) tile[i >> 3][i & 7] = src[(i >> 3) * 128 + (i & 7)];
  __syncthreads();
  int kd = t >> 3, k = t & 7;
  int f = (kd < 8) ? kd : kd + 48;
  float re = 0.f, im = 0.f;
#pragma unroll 8
  for (int d = 0; d < 64; ++d) {
    float2 cs = tw[(d * f) & 63];
    float2 v = tile[d][k];
    re += v.x * cs.x + v.y * cs.y;
    im += v.y * cs.x - v.x * cs.y;
  }
  X3[(size_t)bc * 2048 + kd * 128 + kh * 8 + k] = make_float2(re, im);
}

// ===========================================================================
// Mode mixing
// ===========================================================================
__global__ __launch_bounds__(256) void k_mix(const float2* __restrict__ X3,
                                             const float* __restrict__ wr,
                                             const float* __restrict__ wi,
                                             float2* __restrict__ Y3) {
  __shared__ float2 xs[4][32][8];
  int t = threadIdx.x;
  int kd = blockIdx.x >> 4, kh = blockIdx.x & 15;
  for (int i = t; i < 1024; i += 256) {
    int b = i >> 8, ci = (i >> 3) & 31, k = i & 7;
    xs[b][ci][k] = X3[(size_t)(b * 32 + ci) * 2048 + kd * 128 + kh * 8 + k];
  }
  __syncthreads();
  int corner = ((kd >= 8) ? 2 : 0) + ((kh >= 8) ? 1 : 0);
  int md = kd & 7, mh = kh & 7;
  int co = t >> 3, k = t & 7;
  size_t wbase = (size_t)corner * 32 * 32 * 512 + (size_t)md * 64 + (size_t)mh * 8 + k;
  float ar0 = 0, ai0 = 0, ar1 = 0, ai1 = 0, ar2 = 0, ai2 = 0, ar3 = 0, ai3 = 0;
  for (int ci = 0; ci < 32; ++ci) {
    size_t o = wbase + (size_t)(ci * 32 + co) * 512;
    float wre = wr[o], wim = wi[o];
    float2 v0 = xs[0][ci][k], v1 = xs[1][ci][k];
    float2 v2 = xs[2][ci][k], v3 = xs[3][ci][k];
    ar0 += v0.x * wre - v0.y * wim;  ai0 += v0.x * wim + v0.y * wre;
    ar1 += v1.x * wre - v1.y * wim;  ai1 += v1.x * wim + v1.y * wre;
    ar2 += v2.x * wre - v2.y * wim;  ai2 += v2.x * wim + v2.y * wre;
    ar3 += v3.x * wre - v3.y * wim;  ai3 += v3.x * wim + v3.y * wre;
  }
  size_t obase = (size_t)kd * 128 + kh * 8 + k;
  Y3[(size_t)(0 * 32 + co) * 2048 + obase] = make_float2(ar0, ai0);
  Y3[(size_t)(1 * 32 + co) * 2048 + obase] = make_float2(ar1, ai1);
  Y3[(size_t)(2 * 32 + co) * 2048 + obase] = make_float2(ar2, ai2);
  Y3[(size_t)(3 * 32 + co) * 2048 + obase] = make_float2(ar3, ai3);
}

// ===========================================================================
// Fused inverse DFT along D then H: Y3 -> Z2 (into S buffer)
// ===========================================================================
__global__ __launch_bounds__(256) void k_inv_dh(const float2* __restrict__ Y3,
                                                float2* __restrict__ Z2) {
  __shared__ float2 yt[2048];
  __shared__ float2 zd[4][16][8];
  __shared__ float2 tw[64];
  int t = threadIdx.x;
  if (t < 64) { float s, c; sincosf(TWO_PI_OVER_64 * t, &s, &c); tw[t] = make_float2(c, s); }
  int bc = blockIdx.x >> 4, d0 = (blockIdx.x & 15) * 4;
  const float4* y4 = (const float4*)(Y3 + (size_t)bc * 2048);
  float4* yt4 = (float4*)yt;
  for (int p = 0; p < 4; ++p) yt4[t + 256 * p] = y4[t + 256 * p];
  __syncthreads();
  const float sc = 1.f / 262144.f;
  for (int p = 0; p < 2; ++p) {
    int o = t + 256 * p;
    int dd = o >> 7, kh = (o >> 3) & 15, kw = o & 7;
    int d = d0 + dd;
    float re = 0.f, im = 0.f;
#pragma unroll
    for (int kd = 0; kd < 16; ++kd) {
      int f = (kd < 8) ? kd : kd + 48;
      float2 cs = tw[(d * f) & 63];
      float2 v = yt[kd * 128 + kh * 8 + kw];
      re += v.x * cs.x - v.y * cs.y;
      im += v.x * cs.y + v.y * cs.x;
    }
    zd[dd][kh][kw] = make_float2(re * sc, im * sc);
  }
  __syncthreads();
  for (int p = 0; p < 8; ++p) {
    int o = t + 256 * p;
    int dd = o >> 9, h = (o >> 3) & 63, kw = o & 7;
    float re = 0.f, im = 0.f;
#pragma unroll
    for (int kh = 0; kh < 16; ++kh) {
      int f = (kh < 8) ? kh : kh + 48;
      float2 cs = tw[(h * f) & 63];
      float2 v = zd[dd][kh][kw];
      re += v.x * cs.x - v.y * cs.y;
      im += v.x * cs.y + v.y * cs.x;
    }
    Z2[((size_t)bc * 64 + d0 + dd) * 512 + h * 8 + kw] = make_float2(re, im);
  }
}

// ===========================================================================
// Tail v6: R4's 256-thread/high-occupancy shell, remapped thread work:
// 256 threads = (cog:16, hh:2, ws:8); each thread owns 2 co x 8 w x 1 h.
// Halves xt/zt LDS reads vs R4 at identical LDS footprint and write locality.
// grid = (b, d, h/2) = 8192 blocks.
// MODE 0: inputs = vel/ptt with folded lift+skip; writes x, S (in place)
// MODE 1: inputs = x;                             writes x, S (in place)
// MODE 2: inputs = x;                             channel-sum -> pr (atomics)
// ===========================================================================
template <int MODE>
__global__ __launch_bounds__(256, 4) void k_tail(
    const float2* __restrict__ S, const float* __restrict__ xin,
    const float* __restrict__ pttin, const float* __restrict__ lw,
    const float* __restrict__ lb, const float* __restrict__ skw,
    const float* __restrict__ skb, float* __restrict__ xout,
    float2* __restrict__ Sout, float* __restrict__ pr) {
  __shared__ float2 tws[64];
  __shared__ float2 zt[32][2][9];
  __shared__ float sw[(MODE == 0) ? 3 : 32][32];
  __shared__ float xt[(MODE == 0) ? 2 : 32][2][64];
  int t = threadIdx.x;
  if (t < 64) { float s, c; sincosf(TWO_PI_OVER_64 * t, &s, &c); tws[t] = make_float2(c, s); }
  int b = blockIdx.x >> 11, d = (blockIdx.x >> 5) & 63, h0 = (blockIdx.x & 31) * 2;
  {  // Z2 tile: one float4 per thread
    int co = t >> 3, hh = (t >> 2) & 1, q = t & 3;
    const float4* S4 = (const float4*)S;
    float4 v = S4[(size_t)((b * 32 + co) * 64 + d) * 256 + (h0 + hh) * 4 + q];
    zt[co][hh][2 * q] = make_float2(v.x, v.y);
    zt[co][hh][2 * q + 1] = make_float2(v.z, v.w);
  }
  if constexpr (MODE == 0) {
    if (t < 64) {
      int ch = t >> 5, hh = (t >> 4) & 1, sg = t & 15;
      const float4* src = (const float4*)(ch ? pttin : xin);
      *(float4*)&xt[ch][hh][sg * 4] =
          src[((size_t)b * NSP + d * 4096 + (h0 + hh) * 64) / 4 + sg];
    } else if (t >= 128 && t < 192) {
      int j = (t >> 5) & 1, co = t & 31;
      float a = 0.f;
      for (int ci = 0; ci < 32; ++ci) a += lw[j * 32 + ci] * skw[ci * 32 + co];
      sw[j][co] = a;
    } else if (t >= 192 && t < 224) {
      int co = t & 31;
      float a = skb[co];
      for (int ci = 0; ci < 32; ++ci) a += lb[ci] * skw[ci * 32 + co];
      sw[2][co] = a;
    }
  } else {
    { int ci = t >> 3, q = t & 7;
      *(float4*)&sw[ci][q * 4] = ((const float4*)skw)[t]; }
    for (int p = 0; p < 4; ++p) {
      int idx = t + 256 * p, row = idx >> 4, ci = row >> 1, hh = row & 1, sg = idx & 15;
      *(float4*)&xt[ci][hh][sg * 4] =
          ((const float4*)xin)[(size_t)(((b * 32 + ci) * 64 + d) * 64 + h0 + hh) * 16 + sg];
    }
  }
  __syncthreads();

  int cog = t >> 4, hh = (t >> 3) & 1, ws = t & 7;
  int co0 = 2 * cog;
  float2 e1[8];
#pragma unroll
  for (int j = 0; j < 8; ++j) e1[j] = tws[8 * ws + j];
  float bias[2];
#pragma unroll
  for (int r = 0; r < 2; ++r)
    bias[r] = (MODE == 0) ? sw[2][co0 + r] : skb[co0 + r];

  // ---- irfft along W (twiddle recurrence, 2 co rows) ----
  float acc[2][8];
#pragma unroll
  for (int r = 0; r < 2; ++r) {
    float z0 = zt[co0 + r][hh][0].x + bias[r];
#pragma unroll
    for (int j = 0; j < 8; ++j) acc[r][j] = z0;
  }
  {
    float2 cur[8];
#pragma unroll
    for (int j = 0; j < 8; ++j) cur[j] = e1[j];
#pragma unroll
    for (int k = 1; k < 8; ++k) {
      float2 z0 = zt[co0][hh][k], z1 = zt[co0 + 1][hh][k];
#pragma unroll
      for (int j = 0; j < 8; ++j) {
        acc[0][j] += 2.f * (z0.x * cur[j].x - z0.y * cur[j].y);
        acc[1][j] += 2.f * (z1.x * cur[j].x - z1.y * cur[j].y);
      }
      if (k < 7)
#pragma unroll
        for (int j = 0; j < 8; ++j) {
          float cx = cur[j].x * e1[j].x - cur[j].y * e1[j].y;
          cur[j].y = cur[j].x * e1[j].y + cur[j].y * e1[j].x;
          cur[j].x = cx;
        }
    }
  }
  // ---- skip (32 b128 xt reads: half of R4) ----
  constexpr int NCI = (MODE == 0) ? 2 : 32;
#pragma unroll 4
  for (int ci = 0; ci < NCI; ++ci) {
    float2 sv = *(const float2*)&sw[ci][co0];
    float4 xa = *(const float4*)&xt[ci][hh][8 * ws];
    float4 xb = *(const float4*)&xt[ci][hh][8 * ws + 4];
    float xv[8] = {xa.x, xa.y, xa.z, xa.w, xb.x, xb.y, xb.z, xb.w};
#pragma unroll
    for (int j = 0; j < 8; ++j) {
      acc[0][j] += xv[j] * sv.x;
      acc[1][j] += xv[j] * sv.y;
    }
  }
  // ---- gelu ----
#pragma unroll
  for (int r = 0; r < 2; ++r)
#pragma unroll
    for (int j = 0; j < 8; ++j) {
      float v = acc[r][j];
      float u = 0.7978845608028654f * (v + 0.044715f * v * v * v);
      acc[r][j] = __fdividef(v, 1.f + __expf(-2.f * u));
    }

  if constexpr (MODE == 2) {
    float rs[2];
#pragma unroll
    for (int r = 0; r < 2; ++r) {
      float s = 0.f;
#pragma unroll
      for (int j = 0; j < 8; ++j) s += acc[r][j];
      rs[r] = s;
    }
#pragma unroll
    for (int off = 1; off < 16; off <<= 1)  // reduce over ws(8) and hh(bit 3)
#pragma unroll
      for (int r = 0; r < 2; ++r) rs[r] += __shfl_xor(rs[r], off);
    if ((t & 15) == 0)
#pragma unroll
      for (int r = 0; r < 2; ++r) atomicAdd(&pr[b * 32 + co0 + r], rs[r]);
  } else {
    // ---- write x_{l+1} directly from registers ----
    float4* x4o = (float4*)xout;
#pragma unroll
    for (int r = 0; r < 2; ++r) {
      size_t o = (((size_t)(b * 32 + co0 + r) * 64 + d) * 64 + h0 + hh) * 16 + 2 * ws;
      x4o[o]     = make_float4(acc[r][0], acc[r][1], acc[r][2], acc[r][3]);
      x4o[o + 1] = make_float4(acc[r][4], acc[r][5], acc[r][6], acc[r][7]);
    }
    // ---- fused fwd-W: register partials + reduce-scatter over the 8 ws lanes
    float2 P[2][8];
#pragma unroll
    for (int r = 0; r < 2; ++r)
#pragma unroll
      for (int kw = 0; kw < 8; ++kw) P[r][kw] = make_float2(0.f, 0.f);
#pragma unroll
    for (int j = 0; j < 8; ++j) {
      float2 cc = make_float2(e1[j].x, -e1[j].y);  // e^{-i theta_j}
      float2 cur = make_float2(1.f, 0.f);
      float g0 = acc[0][j], g1 = acc[1][j];
#pragma unroll
      for (int kw = 0; kw < 8; ++kw) {
        P[0][kw].x += g0 * cur.x;  P[0][kw].y += g0 * cur.y;
        P[1][kw].x += g1 * cur.x;  P[1][kw].y += g1 * cur.y;
        if (kw < 7) {
          float cx = cur.x * cc.x - cur.y * cc.y;
          cur.y = cur.x * cc.y + cur.y * cc.x;
          cur.x = cx;
        }
      }
    }
    float2 Q[2][4];
#pragma unroll
    for (int r = 0; r < 2; ++r)
#pragma unroll
      for (int kk = 0; kk < 4; ++kk) {
        float2 keep = (ws & 4) ? P[r][kk + 4] : P[r][kk];
        float2 send = (ws & 4) ? P[r][kk] : P[r][kk + 4];
        keep.x += __shfl_xor(send.x, 4);
        keep.y += __shfl_xor(send.y, 4);
        Q[r][kk] = keep;
      }
    float2 R[2][2];
#pragma unroll
    for (int r = 0; r < 2; ++r)
#pragma unroll
      for (int kk = 0; kk < 2; ++kk) {
        float2 keep = (ws & 2) ? Q[r][kk + 2] : Q[r][kk];
        float2 send = (ws & 2) ? Q[r][kk] : Q[r][kk + 2];
        keep.x += __shfl_xor(send.x, 2);
        keep.y += __shfl_xor(send.y, 2);
        R[r][kk] = keep;
      }
#pragma unroll
    for (int r = 0; r < 2; ++r) {
      float2 keep = (ws & 1) ? R[r][1] : R[r][0];
      float2 send = (ws & 1) ? R[r][0] : R[r][1];
      keep.x += __shfl_xor(send.x, 1);
      keep.y += __shfl_xor(send.y, 1);
      Sout[((size_t)(b * 32 + co0 + r) * 64 + d) * 512 + (h0 + hh) * 8 + ws] = keep;
    }
  }
}

// ===========================================================================
// Head: collapsed layer-4 (DC-only spectral + skip) + proj + MLP -> out[4,3]
// ===========================================================================
__global__ __launch_bounds__(128) void k_head(const float* __restrict__ pr,
                                              const float* __restrict__ swr,
                                              const float* __restrict__ skw,
                                              const float* __restrict__ skb,
                                              const float* __restrict__ pw,
                                              const float* __restrict__ pb,
                                              const float* __restrict__ f1w,
                                              const float* __restrict__ f1b,
                                              const float* __restrict__ f2w,
                                              const float* __restrict__ f2b,
                                              const float* __restrict__ f3w,
                                              const float* __restrict__ f3b,
                                              float* __restrict__ out) {
  __shared__ float m[128], h1[128], p2[128], f1[512], f2[256];
  int t = threadIdx.x;
  m[t] = pr[t] * (1.f / 262144.f);
  __syncthreads();
  { int b = t >> 5, co = t & 31;
    float acc = skb[96 + co];
    for (int ci = 0; ci < 32; ++ci) {
      float wdc = swr[((size_t)12 * 1024 + (size_t)(ci * 32 + co)) * 512];
      acc += m[b * 32 + ci] * (wdc + skw[3072 + ci * 32 + co]);
    }
    h1[t] = acc; }
  __syncthreads();
  { int b = t >> 5, o = t & 31;
    float acc = pb[o];
    for (int c = 0; c < 32; ++c) acc += h1[b * 32 + c] * pw[c * 32 + o];
    p2[t] = acc; }
  __syncthreads();
  for (int j = 0; j < 4; ++j) {
    int idx = t + 128 * j, b = idx >> 7, o = idx & 127;
    float acc = f1b[o];
    for (int c = 0; c < 32; ++c) acc += p2[b * 32 + c] * f1w[c * 128 + o];
    f1[idx] = fmaxf(acc, 0.f);
  }
  __syncthreads();
  for (int j = 0; j < 2; ++j) {
    int idx = t + 128 * j, b = idx >> 6, o = idx & 63;
    float acc = f2b[o];
    for (int c = 0; c < 128; ++c) acc += f1[b * 128 + c] * f2w[c * 64 + o];
    f2[idx] = fmaxf(acc, 0.f);
  }
  __syncthreads();
  if (t < 12) {
    int b = t / 3, o = t % 3;
    float acc = f3b[o];
    for (int c = 0; c < 64; ++c) acc += f2[b * 64 + c] * f3w[c * 3 + o];
    out[t] = acc;
  }
}

// ===========================================================================
extern "C" void kernel_launch(void* const* d_in, const int* in_sizes, int n_in,
                              void* d_out, int out_size, void* d_ws, size_t ws_size,
                              hipStream_t stream) {
  const float* vel = (const float*)d_in[0];
  const float* ptt = (const float*)d_in[1];
  const float* lw  = (const float*)d_in[2];
  const float* lb  = (const float*)d_in[3];
  const float* swr = (const float*)d_in[4];
  const float* swi = (const float*)d_in[5];
  const float* skw = (const float*)d_in[6];
  const float* skb = (const float*)d_in[7];
  const float* pw  = (const float*)d_in[8];
  const float* pb  = (const float*)d_in[9];
  const float* f1w = (const float*)d_in[10];
  const float* f1b = (const float*)d_in[11];
  const float* f2w = (const float*)d_in[12];
  const float* f2b = (const float*)d_in[13];
  const float* f3w = (const float*)d_in[14];
  const float* f3b = (const float*)d_in[15];
  float* out = (float*)d_out;

  char* ws = (char*)d_ws;
  float*  x   = (float*)(ws);
  float2* S   = (float2*)(ws + 134217728ULL);
  float2* X2  = (float2*)(ws + 167772160ULL);
  float2* VP2 = X2;
  float2* X3  = (float2*)(ws + 176160768ULL);
  float2* Y3  = (float2*)(ws + 178257920ULL);
  float*  pr  = (float*)(ws + 180355072ULL);
  if (ws_size < 180355584ULL) return;

  hipMemsetAsync(pr, 0, 512, stream);

  // ---- layer 0 (lift folded into the 2-channel spectral path) ----
  k_fwd_wh2<<<512, 256, 0, stream>>>(vel, ptt, VP2);
  k_fwd_d_lift<<<64, 256, 0, stream>>>(VP2, lw, lb, X3);
  k_mix<<<256, 256, 0, stream>>>(X3, swr, swi, Y3);
  k_inv_dh<<<2048, 256, 0, stream>>>(Y3, S);
  k_tail<0><<<8192, 256, 0, stream>>>(S, vel, ptt, lw, lb, skw, skb, x, S, nullptr);

  // ---- layer 1 ----
  k_fwd_h<<<8192, 128, 0, stream>>>(S, X2);
  k_fwd_d<<<2048, 128, 0, stream>>>(X2, X3);
  k_mix<<<256, 256, 0, stream>>>(X3, swr + 2097152, swi + 2097152, Y3);
  k_inv_dh<<<2048, 256, 0, stream>>>(Y3, S);
  k_tail<1><<<8192, 256, 0, stream>>>(S, x, nullptr, nullptr, nullptr,
                                      skw + 1024, skb + 32, x, S, nullptr);

  // ---- layer 2 (mean fused, no x/X1 writeback) ----
  k_fwd_h<<<8192, 128, 0, stream>>>(S, X2);
  k_fwd_d<<<2048, 128, 0, stream>>>(X2, X3);
  k_mix<<<256, 256, 0, stream>>>(X3, swr + 2 * 2097152, swi + 2 * 2097152, Y3);
  k_inv_dh<<<2048, 256, 0, stream>>>(Y3, S);
  k_tail<2><<<8192, 256, 0, stream>>>(S, x, nullptr, nullptr, nullptr,
                                      skw + 2048, skb + 64, nullptr, nullptr, pr);

  // ---- collapsed layer 3 + proj + MLP head ----
  k_head<<<1, 128, 0, stream>>>(pr, swr, skw, skb, pw, pb, f1w, f1b,
                                f2w, f2b, f3w, f3b, out);
}

// Round 7
// 704.890 us; speedup vs baseline: 1.4394x; 1.1848x over previous
//
#include <hip/hip_runtime.h>
#include <math.h>

#define NSP 262144  // 64^3
static constexpr float TWO_PI_OVER_64 = 0.09817477042468103f;

// ===========================================================================
// Layer-0 front end: DFT (W then H) of the 2 raw input channels.
// ===========================================================================
__global__ __launch_bounds__(256) void k_fwd_wh2(const float* __restrict__ vel,
                                                 const float* __restrict__ ptt,
                                                 float2* __restrict__ VP2) {
  __shared__ float plane[64][65];
  __shared__ float2 A[64][8];
  __shared__ float2 tw[64];
  int t = threadIdx.x;
  if (t < 64) { float s, c; sincosf(TWO_PI_OVER_64 * t, &s, &c); tw[t] = make_float2(c, s); }
  int b = blockIdx.x >> 7, ch = (blockIdx.x >> 6) & 1, d = blockIdx.x & 63;
  const float4* src = (const float4*)((ch ? ptt : vel) + (size_t)b * NSP + d * 4096);
  for (int p = 0; p < 4; ++p) {
    int i = t + 256 * p;
    float4 v = src[i];
    int h = i >> 4, sg = (i & 15) * 4;
    plane[h][sg] = v.x; plane[h][sg + 1] = v.y; plane[h][sg + 2] = v.z; plane[h][sg + 3] = v.w;
  }
  __syncthreads();
  for (int p = 0; p < 2; ++p) {
    int o = t + 256 * p;
    int h = o >> 3, kw = o & 7;
    float re = 0.f, im = 0.f;
    for (int w = 0; w < 64; ++w) {
      float2 cs = tw[(kw * w) & 63];
      float v = plane[h][w];
      re += v * cs.x; im -= v * cs.y;
    }
    A[h][kw] = make_float2(re, im);
  }
  __syncthreads();
  if (t < 128) {
    int kh = t >> 3, kw = t & 7;
    int f = (kh < 8) ? kh : kh + 48;
    float re = 0.f, im = 0.f;
    for (int h = 0; h < 64; ++h) {
      float2 cs = tw[(h * f) & 63];
      float2 a = A[h][kw];
      re += a.x * cs.x + a.y * cs.y;
      im += a.y * cs.x - a.x * cs.y;
    }
    VP2[(size_t)blockIdx.x * 128 + t] = make_float2(re, im);
  }
}

// ===========================================================================
// Layer-0: DFT along D of the 2 channels + fold lift -> X3[b,ci,kd,kh,kw]
// ===========================================================================
__global__ __launch_bounds__(256) void k_fwd_d_lift(const float2* __restrict__ VP2,
                                                    const float* __restrict__ lw,
                                                    const float* __restrict__ lb,
                                                    float2* __restrict__ X3) {
  __shared__ float2 tile[2][64][8];
  __shared__ float2 F[2][16][8];
  __shared__ float2 tw[64];
  int t = threadIdx.x;
  if (t < 64) { float s, c; sincosf(TWO_PI_OVER_64 * t, &s, &c); tw[t] = make_float2(c, s); }
  int b = blockIdx.x >> 4, kh = blockIdx.x & 15;
  for (int p = 0; p < 4; ++p) {
    int i = t + 256 * p;
    int ch = i >> 9, dd = (i >> 3) & 63, kw = i & 7;
    tile[ch][dd][kw] = VP2[(size_t)((b * 2 + ch) * 64 + dd) * 128 + kh * 8 + kw];
  }
  __syncthreads();
  { int ch = t >> 7, kd = (t >> 3) & 15, kw = t & 7;
    int f = (kd < 8) ? kd : kd + 48;
    float re = 0.f, im = 0.f;
    for (int dd = 0; dd < 64; ++dd) {
      float2 cs = tw[(dd * f) & 63];
      float2 v = tile[ch][dd][kw];
      re += v.x * cs.x + v.y * cs.y;
      im += v.y * cs.x - v.x * cs.y;
    }
    F[ch][kd][kw] = make_float2(re, im); }
  __syncthreads();
  for (int p = 0; p < 16; ++p) {
    int o = t + 256 * p;
    int ci = o >> 7, kd = (o >> 3) & 15, kw = o & 7;
    float2 f0 = F[0][kd][kw], f1 = F[1][kd][kw];
    float w0 = lw[ci], w1 = lw[32 + ci];
    float2 v = make_float2(w0 * f0.x + w1 * f1.x, w0 * f0.y + w1 * f1.y);
    if (kh == 0 && kd == 0 && kw == 0) v.x += lb[ci] * 262144.f;
    X3[(size_t)(b * 32 + ci) * 2048 + kd * 128 + kh * 8 + kw] = v;
  }
}

// ===========================================================================
// Forward DFT along H (layers 1,2): X1 -> X2  (table gather — R2 version)
// ===========================================================================
__global__ __launch_bounds__(128) void k_fwd_h(const float2* __restrict__ X1,
                                               float2* __restrict__ X2) {
  __shared__ float2 tile[64][8];
  __shared__ float2 tw[64];
  int t = threadIdx.x;
  if (t < 64) { float s, c; sincosf(TWO_PI_OVER_64 * t, &s, &c); tw[t] = make_float2(c, s); }
  const float4* s4 = (const float4*)(X1 + (size_t)blockIdx.x * 512);
  float4* t4 = (float4*)tile;
  t4[t] = s4[t];
  t4[t + 128] = s4[t + 128];
  __syncthreads();
  int kh = t >> 3, k = t & 7;
  int f = (kh < 8) ? kh : kh + 48;
  float re = 0.f, im = 0.f;
#pragma unroll 8
  for (int h = 0; h < 64; ++h) {
    float2 cs = tw[(h * f) & 63];
    float2 v = tile[h][k];
    re += v.x * cs.x + v.y * cs.y;
    im += v.y * cs.x - v.x * cs.y;
  }
  X2[(size_t)blockIdx.x * 128 + t] = make_float2(re, im);
}

// ===========================================================================
// Forward DFT along D (layers 1,2): X2 -> X3  (table gather — R2 version)
// ===========================================================================
__global__ __launch_bounds__(128) void k_fwd_d(const float2* __restrict__ X2,
                                               float2* __restrict__ X3) {
  __shared__ float2 tile[64][8];
  __shared__ float2 tw[64];
  int t = threadIdx.x;
  if (t < 64) { float s, c; sincosf(TWO_PI_OVER_64 * t, &s, &c); tw[t] = make_float2(c, s); }
  int kh = blockIdx.x & 15, bc = blockIdx.x >> 4;
  const float2* src = X2 + (size_t)bc * 8192 + kh * 8;
  for (int i = t; i < 512; i += 128) tile[i >> 3][i & 7] = src[(i >> 3) * 128 + (i & 7)];
  __syncthreads();
  int kd = t >> 3, k = t & 7;
  int f = (kd < 8) ? kd : kd + 48;
  float re = 0.f, im = 0.f;
#pragma unroll 8
  for (int d = 0; d < 64; ++d) {
    float2 cs = tw[(d * f) & 63];
    float2 v = tile[d][k];
    re += v.x * cs.x + v.y * cs.y;
    im += v.y * cs.x - v.x * cs.y;
  }
  X3[(size_t)bc * 2048 + kd * 128 + kh * 8 + k] = make_float2(re, im);
}

// ===========================================================================
// Mode mixing
// ===========================================================================
__global__ __launch_bounds__(256) void k_mix(const float2* __restrict__ X3,
                                             const float* __restrict__ wr,
                                             const float* __restrict__ wi,
                                             float2* __restrict__ Y3) {
  __shared__ float2 xs[4][32][8];
  int t = threadIdx.x;
  int kd = blockIdx.x >> 4, kh = blockIdx.x & 15;
  for (int i = t; i < 1024; i += 256) {
    int b = i >> 8, ci = (i >> 3) & 31, k = i & 7;
    xs[b][ci][k] = X3[(size_t)(b * 32 + ci) * 2048 + kd * 128 + kh * 8 + k];
  }
  __syncthreads();
  int corner = ((kd >= 8) ? 2 : 0) + ((kh >= 8) ? 1 : 0);
  int md = kd & 7, mh = kh & 7;
  int co = t >> 3, k = t & 7;
  size_t wbase = (size_t)corner * 32 * 32 * 512 + (size_t)md * 64 + (size_t)mh * 8 + k;
  float ar0 = 0, ai0 = 0, ar1 = 0, ai1 = 0, ar2 = 0, ai2 = 0, ar3 = 0, ai3 = 0;
  for (int ci = 0; ci < 32; ++ci) {
    size_t o = wbase + (size_t)(ci * 32 + co) * 512;
    float wre = wr[o], wim = wi[o];
    float2 v0 = xs[0][ci][k], v1 = xs[1][ci][k];
    float2 v2 = xs[2][ci][k], v3 = xs[3][ci][k];
    ar0 += v0.x * wre - v0.y * wim;  ai0 += v0.x * wim + v0.y * wre;
    ar1 += v1.x * wre - v1.y * wim;  ai1 += v1.x * wim + v1.y * wre;
    ar2 += v2.x * wre - v2.y * wim;  ai2 += v2.x * wim + v2.y * wre;
    ar3 += v3.x * wre - v3.y * wim;  ai3 += v3.x * wim + v3.y * wre;
  }
  size_t obase = (size_t)kd * 128 + kh * 8 + k;
  Y3[(size_t)(0 * 32 + co) * 2048 + obase] = make_float2(ar0, ai0);
  Y3[(size_t)(1 * 32 + co) * 2048 + obase] = make_float2(ar1, ai1);
  Y3[(size_t)(2 * 32 + co) * 2048 + obase] = make_float2(ar2, ai2);
  Y3[(size_t)(3 * 32 + co) * 2048 + obase] = make_float2(ar3, ai3);
}

// ===========================================================================
// Fused inverse DFT along D then H: Y3 -> Z2 (into S buffer)
// ===========================================================================
__global__ __launch_bounds__(256) void k_inv_dh(const float2* __restrict__ Y3,
                                                float2* __restrict__ Z2) {
  __shared__ float2 yt[2048];
  __shared__ float2 zd[4][16][8];
  __shared__ float2 tw[64];
  int t = threadIdx.x;
  if (t < 64) { float s, c; sincosf(TWO_PI_OVER_64 * t, &s, &c); tw[t] = make_float2(c, s); }
  int bc = blockIdx.x >> 4, d0 = (blockIdx.x & 15) * 4;
  const float4* y4 = (const float4*)(Y3 + (size_t)bc * 2048);
  float4* yt4 = (float4*)yt;
  for (int p = 0; p < 4; ++p) yt4[t + 256 * p] = y4[t + 256 * p];
  __syncthreads();
  const float sc = 1.f / 262144.f;
  for (int p = 0; p < 2; ++p) {
    int o = t + 256 * p;
    int dd = o >> 7, kh = (o >> 3) & 15, kw = o & 7;
    int d = d0 + dd;
    float re = 0.f, im = 0.f;
#pragma unroll
    for (int kd = 0; kd < 16; ++kd) {
      int f = (kd < 8) ? kd : kd + 48;
      float2 cs = tw[(d * f) & 63];
      float2 v = yt[kd * 128 + kh * 8 + kw];
      re += v.x * cs.x - v.y * cs.y;
      im += v.x * cs.y + v.y * cs.x;
    }
    zd[dd][kh][kw] = make_float2(re * sc, im * sc);
  }
  __syncthreads();
  for (int p = 0; p < 8; ++p) {
    int o = t + 256 * p;
    int dd = o >> 9, h = (o >> 3) & 63, kw = o & 7;
    float re = 0.f, im = 0.f;
#pragma unroll
    for (int kh = 0; kh < 16; ++kh) {
      int f = (kh < 8) ? kh : kh + 48;
      float2 cs = tw[(h * f) & 63];
      float2 v = zd[dd][kh][kw];
      re += v.x * cs.x - v.y * cs.y;
      im += v.x * cs.y + v.y * cs.x;
    }
    Z2[((size_t)bc * 64 + d0 + dd) * 512 + h * 8 + kw] = make_float2(re, im);
  }
}

// ===========================================================================
// Tail v4 (verbatim round-4 version — proven 178 us): 256 threads = (co:32,
// ws:8), 2 h rows/thread.  irfft twiddles by register recurrence; fwd-W by
// register partials + 8-lane reduce-scatter shuffle.  grid = (b,d,h/2)=8192.
// MODE 0: inputs = vel/ptt with folded lift+skip; writes x, S (in place)
// MODE 1: inputs = x;                             writes x, S (in place)
// MODE 2: inputs = x;                             channel-sum -> pr (atomics)
// ===========================================================================
template <int MODE>
__global__ __launch_bounds__(256, 4) void k_tail(
    const float2* __restrict__ S, const float* __restrict__ xin,
    const float* __restrict__ pttin, const float* __restrict__ lw,
    const float* __restrict__ lb, const float* __restrict__ skw,
    const float* __restrict__ skb, float* __restrict__ xout,
    float2* __restrict__ Sout, float* __restrict__ pr) {
  __shared__ float2 tws[64];
  __shared__ float2 zt[32][2][9];
  __shared__ float sw[(MODE == 0) ? 3 : 32][32];
  __shared__ float xt[(MODE == 0) ? 2 : 32][2][64];
  int t = threadIdx.x;
  if (t < 64) { float s, c; sincosf(TWO_PI_OVER_64 * t, &s, &c); tws[t] = make_float2(c, s); }
  int b = blockIdx.x >> 11, d = (blockIdx.x >> 5) & 63, h0 = (blockIdx.x & 31) * 2;
  {  // Z2 tile
    int co = t >> 3, hh = (t >> 2) & 1, q = t & 3;
    const float4* S4 = (const float4*)S;
    float4 v = S4[(size_t)((b * 32 + co) * 64 + d) * 256 + (h0 + hh) * 4 + q];
    zt[co][hh][2 * q] = make_float2(v.x, v.y);
    zt[co][hh][2 * q + 1] = make_float2(v.z, v.w);
  }
  if constexpr (MODE == 0) {
    if (t < 64) {
      int ch = t >> 5, hh = (t >> 4) & 1, sg = t & 15;
      const float4* src = (const float4*)(ch ? pttin : xin);
      *(float4*)&xt[ch][hh][sg * 4] =
          src[((size_t)b * NSP + d * 4096 + (h0 + hh) * 64) / 4 + sg];
    } else if (t >= 128 && t < 192) {
      int j = (t >> 5) & 1, co = t & 31;
      float a = 0.f;
      for (int ci = 0; ci < 32; ++ci) a += lw[j * 32 + ci] * skw[ci * 32 + co];
      sw[j][co] = a;
    } else if (t >= 192 && t < 224) {
      int co = t & 31;
      float a = skb[co];
      for (int ci = 0; ci < 32; ++ci) a += lb[ci] * skw[ci * 32 + co];
      sw[2][co] = a;
    }
  } else {
    { int ci = t >> 3, q = t & 7;
      *(float4*)&sw[ci][q * 4] = ((const float4*)skw)[t]; }
    for (int p = 0; p < 4; ++p) {
      int idx = t + 256 * p, row = idx >> 4, ci = row >> 1, hh = row & 1, sg = idx & 15;
      *(float4*)&xt[ci][hh][sg * 4] =
          ((const float4*)xin)[(size_t)(((b * 32 + ci) * 64 + d) * 64 + h0 + hh) * 16 + sg];
    }
  }
  __syncthreads();

  int co = t >> 3, ws = t & 7;
  float2 e1[8];
#pragma unroll
  for (int j = 0; j < 8; ++j) e1[j] = tws[8 * ws + j];
  float bias = (MODE == 0) ? sw[2][co] : skb[co];

  // ---- irfft along W (twiddle recurrence) ----
  float acc[2][8];
  {
    float z00 = zt[co][0][0].x, z10 = zt[co][1][0].x;
#pragma unroll
    for (int j = 0; j < 8; ++j) { acc[0][j] = bias + z00; acc[1][j] = bias + z10; }
  }
  {
    float2 cur[8];
#pragma unroll
    for (int j = 0; j < 8; ++j) cur[j] = e1[j];
#pragma unroll
    for (int k = 1; k < 8; ++k) {
      float2 z0 = zt[co][0][k], z1 = zt[co][1][k];
#pragma unroll
      for (int j = 0; j < 8; ++j) {
        acc[0][j] += 2.f * (z0.x * cur[j].x - z0.y * cur[j].y);
        acc[1][j] += 2.f * (z1.x * cur[j].x - z1.y * cur[j].y);
      }
      if (k < 7)
#pragma unroll
        for (int j = 0; j < 8; ++j) {
          float cx = cur[j].x * e1[j].x - cur[j].y * e1[j].y;
          cur[j].y = cur[j].x * e1[j].y + cur[j].y * e1[j].x;
          cur[j].x = cx;
        }
    }
  }
  // ---- skip ----
  constexpr int NCI = (MODE == 0) ? 2 : 32;
#pragma unroll 4
  for (int ci = 0; ci < NCI; ++ci) {
    float s = sw[ci][co];
#pragma unroll
    for (int hh = 0; hh < 2; ++hh) {
      float4 xa = *(const float4*)&xt[ci][hh][8 * ws];
      float4 xb = *(const float4*)&xt[ci][hh][8 * ws + 4];
      acc[hh][0] += xa.x * s;  acc[hh][1] += xa.y * s;
      acc[hh][2] += xa.z * s;  acc[hh][3] += xa.w * s;
      acc[hh][4] += xb.x * s;  acc[hh][5] += xb.y * s;
      acc[hh][6] += xb.z * s;  acc[hh][7] += xb.w * s;
    }
  }
  // ---- gelu ----
#pragma unroll
  for (int hh = 0; hh < 2; ++hh)
#pragma unroll
    for (int j = 0; j < 8; ++j) {
      float v = acc[hh][j];
      float u = 0.7978845608028654f * (v + 0.044715f * v * v * v);
      acc[hh][j] = __fdividef(v, 1.f + __expf(-2.f * u));
    }

  if constexpr (MODE == 2) {
    float s = 0.f;
#pragma unroll
    for (int hh = 0; hh < 2; ++hh)
#pragma unroll
      for (int j = 0; j < 8; ++j) s += acc[hh][j];
    s += __shfl_down(s, 4, 8);
    s += __shfl_down(s, 2, 8);
    s += __shfl_down(s, 1, 8);
    if (ws == 0) atomicAdd(&pr[b * 32 + co], s);
  } else {
    // ---- write x_{l+1} directly from registers ----
    float4* x4o = (float4*)xout;
#pragma unroll
    for (int hh = 0; hh < 2; ++hh) {
      size_t o = (((size_t)(b * 32 + co) * 64 + d) * 64 + h0 + hh) * 16 + 2 * ws;
      x4o[o]     = make_float4(acc[hh][0], acc[hh][1], acc[hh][2], acc[hh][3]);
      x4o[o + 1] = make_float4(acc[hh][4], acc[hh][5], acc[hh][6], acc[hh][7]);
    }
    // ---- fused fwd-W: register partials + reduce-scatter over the 8 ws lanes
    float2 P[2][8];
#pragma unroll
    for (int hh = 0; hh < 2; ++hh)
#pragma unroll
      for (int kw = 0; kw < 8; ++kw) P[hh][kw] = make_float2(0.f, 0.f);
#pragma unroll
    for (int j = 0; j < 8; ++j) {
      float2 cc = make_float2(e1[j].x, -e1[j].y);  // e^{-i theta_j}
      float2 cur = make_float2(1.f, 0.f);
      float g0 = acc[0][j], g1 = acc[1][j];
#pragma unroll
      for (int kw = 0; kw < 8; ++kw) {
        P[0][kw].x += g0 * cur.x;  P[0][kw].y += g0 * cur.y;
        P[1][kw].x += g1 * cur.x;  P[1][kw].y += g1 * cur.y;
        if (kw < 7) {
          float cx = cur.x * cc.x - cur.y * cc.y;
          cur.y = cur.x * cc.y + cur.y * cc.x;
          cur.x = cx;
        }
      }
    }
    float2 Q[2][4];
#pragma unroll
    for (int hh = 0; hh < 2; ++hh)
#pragma unroll
      for (int kk = 0; kk < 4; ++kk) {
        float2 keep = (ws & 4) ? P[hh][kk + 4] : P[hh][kk];
        float2 send = (ws & 4) ? P[hh][kk] : P[hh][kk + 4];
        keep.x += __shfl_xor(send.x, 4);
        keep.y += __shfl_xor(send.y, 4);
        Q[hh][kk] = keep;
      }
    float2 R[2][2];
#pragma unroll
    for (int hh = 0; hh < 2; ++hh)
#pragma unroll
      for (int kk = 0; kk < 2; ++kk) {
        float2 keep = (ws & 2) ? Q[hh][kk + 2] : Q[hh][kk];
        float2 send = (ws & 2) ? Q[hh][kk] : Q[hh][kk + 2];
        keep.x += __shfl_xor(send.x, 2);
        keep.y += __shfl_xor(send.y, 2);
        R[hh][kk] = keep;
      }
#pragma unroll
    for (int hh = 0; hh < 2; ++hh) {
      float2 keep = (ws & 1) ? R[hh][1] : R[hh][0];
      float2 send = (ws & 1) ? R[hh][0] : R[hh][1];
      keep.x += __shfl_xor(send.x, 1);
      keep.y += __shfl_xor(send.y, 1);
      Sout[((size_t)(b * 32 + co) * 64 + d) * 512 + (h0 + hh) * 8 + ws] = keep;
    }
  }
}

// ===========================================================================
// Head: collapsed layer-4 (DC-only spectral + skip) + proj + MLP -> out[4,3]
// ===========================================================================
__global__ __launch_bounds__(128) void k_head(const float* __restrict__ pr,
                                              const float* __restrict__ swr,
                                              const float* __restrict__ skw,
                                              const float* __restrict__ skb,
                                              const float* __restrict__ pw,
                                              const float* __restrict__ pb,
                                              const float* __restrict__ f1w,
                                              const float* __restrict__ f1b,
                                              const float* __restrict__ f2w,
                                              const float* __restrict__ f2b,
                                              const float* __restrict__ f3w,
                                              const float* __restrict__ f3b,
                                              float* __restrict__ out) {
  __shared__ float m[128], h1[128], p2[128], f1[512], f2[256];
  int t = threadIdx.x;
  m[t] = pr[t] * (1.f / 262144.f);
  __syncthreads();
  { int b = t >> 5, co = t & 31;
    float acc = skb[96 + co];
    for (int ci = 0; ci < 32; ++ci) {
      float wdc = swr[((size_t)12 * 1024 + (size_t)(ci * 32 + co)) * 512];
      acc += m[b * 32 + ci] * (wdc + skw[3072 + ci * 32 + co]);
    }
    h1[t] = acc; }
  __syncthreads();
  { int b = t >> 5, o = t & 31;
    float acc = pb[o];
    for (int c = 0; c < 32; ++c) acc += h1[b * 32 + c] * pw[c * 32 + o];
    p2[t] = acc; }
  __syncthreads();
  for (int j = 0; j < 4; ++j) {
    int idx = t + 128 * j, b = idx >> 7, o = idx & 127;
    float acc = f1b[o];
    for (int c = 0; c < 32; ++c) acc += p2[b * 32 + c] * f1w[c * 128 + o];
    f1[idx] = fmaxf(acc, 0.f);
  }
  __syncthreads();
  for (int j = 0; j < 2; ++j) {
    int idx = t + 128 * j, b = idx >> 6, o = idx & 63;
    float acc = f2b[o];
    for (int c = 0; c < 128; ++c) acc += f1[b * 128 + c] * f2w[c * 64 + o];
    f2[idx] = fmaxf(acc, 0.f);
  }
  __syncthreads();
  if (t < 12) {
    int b = t / 3, o = t % 3;
    float acc = f3b[o];
    for (int c = 0; c < 64; ++c) acc += f2[b * 64 + c] * f3w[c * 3 + o];
    out[t] = acc;
  }
}

// ===========================================================================
extern "C" void kernel_launch(void* const* d_in, const int* in_sizes, int n_in,
                              void* d_out, int out_size, void* d_ws, size_t ws_size,
                              hipStream_t stream) {
  const float* vel = (const float*)d_in[0];
  const float* ptt = (const float*)d_in[1];
  const float* lw  = (const float*)d_in[2];
  const float* lb  = (const float*)d_in[3];
  const float* swr = (const float*)d_in[4];
  const float* swi = (const float*)d_in[5];
  const float* skw = (const float*)d_in[6];
  const float* skb = (const float*)d_in[7];
  const float* pw  = (const float*)d_in[8];
  const float* pb  = (const float*)d_in[9];
  const float* f1w = (const float*)d_in[10];
  const float* f1b = (const float*)d_in[11];
  const float* f2w = (const float*)d_in[12];
  const float* f2b = (const float*)d_in[13];
  const float* f3w = (const float*)d_in[14];
  const float* f3b = (const float*)d_in[15];
  float* out = (float*)d_out;

  char* ws = (char*)d_ws;
  float*  x   = (float*)(ws);
  float2* S   = (float2*)(ws + 134217728ULL);
  float2* X2  = (float2*)(ws + 167772160ULL);
  float2* VP2 = X2;
  float2* X3  = (float2*)(ws + 176160768ULL);
  float2* Y3  = (float2*)(ws + 178257920ULL);
  float*  pr  = (float*)(ws + 180355072ULL);
  if (ws_size < 180355584ULL) return;

  hipMemsetAsync(pr, 0, 512, stream);

  // ---- layer 0 (lift folded into the 2-channel spectral path) ----
  k_fwd_wh2<<<512, 256, 0, stream>>>(vel, ptt, VP2);
  k_fwd_d_lift<<<64, 256, 0, stream>>>(VP2, lw, lb, X3);
  k_mix<<<256, 256, 0, stream>>>(X3, swr, swi, Y3);
  k_inv_dh<<<2048, 256, 0, stream>>>(Y3, S);
  k_tail<0><<<8192, 256, 0, stream>>>(S, vel, ptt, lw, lb, skw, skb, x, S, nullptr);

  // ---- layer 1 ----
  k_fwd_h<<<8192, 128, 0, stream>>>(S, X2);
  k_fwd_d<<<2048, 128, 0, stream>>>(X2, X3);
  k_mix<<<256, 256, 0, stream>>>(X3, swr + 2097152, swi + 2097152, Y3);
  k_inv_dh<<<2048, 256, 0, stream>>>(Y3, S);
  k_tail<1><<<8192, 256, 0, stream>>>(S, x, nullptr, nullptr, nullptr,
                                      skw + 1024, skb + 32, x, S, nullptr);

  // ---- layer 2 (mean fused, no x/X1 writeback) ----
  k_fwd_h<<<8192, 128, 0, stream>>>(S, X2);
  k_fwd_d<<<2048, 128, 0, stream>>>(X2, X3);
  k_mix<<<256, 256, 0, stream>>>(X3, swr + 2 * 2097152, swi + 2 * 2097152, Y3);
  k_inv_dh<<<2048, 256, 0, stream>>>(Y3, S);
  k_tail<2><<<8192, 256, 0, stream>>>(S, x, nullptr, nullptr, nullptr,
                                      skw + 2048, skb + 64, nullptr, nullptr, pr);

  // ---- collapsed layer 3 + proj + MLP head ----
  k_head<<<1, 128, 0, stream>>>(pr, swr, skw, skb, pw, pb, f1w, f1b,
                                f2w, f2b, f3w, f3b, out);
}